// Round 7
// baseline (275.088 us; speedup 1.0000x reference)
//
#include <hip/hip_runtime.h>
#include <cmath>

typedef __attribute__((ext_vector_type(8))) short bf16x8;
typedef __attribute__((ext_vector_type(4))) float f32x4;

// ---------- bf16 pack/unpack ----------
static __device__ __forceinline__ unsigned short f2bf(float f) {
    unsigned u = __float_as_uint(f);
    unsigned r = (u + 0x7fffu + ((u >> 16) & 1u)) >> 16;   // RNE
    return (unsigned short)r;
}
static __device__ __forceinline__ unsigned packbf(float a, float b) {
    return (unsigned)f2bf(a) | ((unsigned)f2bf(b) << 16);
}
static __device__ __forceinline__ float bflo(unsigned u) { return __uint_as_float(u << 16); }
static __device__ __forceinline__ float bfhi(unsigned u) { return __uint_as_float(u & 0xffff0000u); }

// ---------- fused prep: x->bf16, W1/W2 transpose->bf16, deg=1 ----------
__global__ void prep_k(const float* __restrict__ x, const float* __restrict__ W1,
                       const float* __restrict__ W2, unsigned* __restrict__ xb,
                       unsigned short* __restrict__ Wt1, unsigned short* __restrict__ Wt2,
                       int* __restrict__ deg, int NX2, int NW1, int NW2, int N) {
    int i = blockIdx.x * blockDim.x + threadIdx.x;
    if (i < NX2) {
        float2 v = reinterpret_cast<const float2*>(x)[i];
        xb[i] = packbf(v.x, v.y);
        return;
    }
    i -= NX2;
    if (i < NW1) { int nn = i / 128, k = i % 128; Wt1[i] = f2bf(W1[(size_t)k * 256 + nn]); return; }
    i -= NW1;
    if (i < NW2) { int nn = i / 256, k = i % 256; Wt2[i] = f2bf(W2[(size_t)k * 128 + nn]); return; }
    i -= NW2;
    if (i < N) deg[i] = 1;   // self-loop
}

// ---------- CSR build ----------
__global__ void count_k(const int* __restrict__ dst, int E, int* __restrict__ deg) {
    int e = blockIdx.x * blockDim.x + threadIdx.x;
    if (e < E) atomicAdd(&deg[dst[e]], 1);
}

#define SCAN_BLK 256
#define SCAN_ELEMS 2048

__global__ void scan1_k(const int* __restrict__ deg, int* __restrict__ rowstart,
                        int* __restrict__ bsums, int N) {
    __shared__ int sh[SCAN_BLK];
    int t = threadIdx.x;
    int base = blockIdx.x * SCAN_ELEMS + t * 8;
    int vals[8];
    int sum = 0;
#pragma unroll
    for (int i = 0; i < 8; ++i) {
        int idx = base + i;
        vals[i] = (idx < N) ? deg[idx] : 0;
        sum += vals[i];
    }
    sh[t] = sum;
    __syncthreads();
    for (int off = 1; off < SCAN_BLK; off <<= 1) {
        int v = (t >= off) ? sh[t - off] : 0;
        __syncthreads();
        sh[t] += v;
        __syncthreads();
    }
    int run = sh[t] - sum;
    if (t == SCAN_BLK - 1) bsums[blockIdx.x] = sh[t];
#pragma unroll
    for (int i = 0; i < 8; ++i) {
        int idx = base + i;
        if (idx < N) rowstart[idx] = run;
        run += vals[i];
    }
}
__global__ void scan2_k(int* __restrict__ bsums, int nb) {
    if (threadIdx.x == 0 && blockIdx.x == 0) {
        int run = 0;
        for (int i = 0; i < nb; ++i) { int t = bsums[i]; bsums[i] = run; run += t; }
    }
}
// scan3 + initadj fused: finalize rowstart, place self-loop, set cursor
__global__ void scan3_init_k(int* __restrict__ rowstart, const int* __restrict__ bsums,
                             int* __restrict__ adj, int* __restrict__ cursor, int N, int total) {
    int i = blockIdx.x * blockDim.x + threadIdx.x;
    if (i < N) {
        int r = rowstart[i] + bsums[i / SCAN_ELEMS];
        rowstart[i] = r;
        adj[r] = i;
        cursor[i] = r + 1;
    } else if (i == N) {
        rowstart[N] = total;
    }
}
__global__ void scatter_k(const int* __restrict__ src, const int* __restrict__ dst, int E,
                          int* __restrict__ cursor, int* __restrict__ adj) {
    int e = blockIdx.x * blockDim.x + threadIdx.x;
    if (e >= E) return;
    int pos = atomicAdd(&cursor[dst[e]], 1);
    adj[pos] = src[e];
}

// ---------- MFMA GEMM: Yb[N,NOUT](bf16) = Ab[N,K](bf16) @ Wt[NOUT,K](bf16)^T ----------
template<int K, int NOUT>
__global__ __launch_bounds__(256) void gemm_mfma_k(const unsigned* __restrict__ Ab,
                                                   const unsigned* __restrict__ Bt,
                                                   unsigned short* __restrict__ Yb, int N) {
    __shared__ unsigned short As[128 * 64];
    __shared__ unsigned short Bs[64 * 64];
    int tid = threadIdx.x;
    int lane = tid & 63, wid = tid >> 6;
    int wm = wid >> 1, wc = wid & 1;
    int m0 = blockIdx.x * 128;
    int n0 = blockIdx.y * 64;

    f32x4 acc[4][2] = {};

    for (int k0 = 0; k0 < K; k0 += 64) {
#pragma unroll
        for (int p = 0; p < 4; ++p) {
            int gl = p * 256 + tid;
            int row = gl >> 3, g = gl & 7;
            int grow = m0 + row; if (grow >= N) grow = N - 1;
            uint4 v = *reinterpret_cast<const uint4*>(Ab + (size_t)grow * (K / 2) + k0 / 2 + g * 4);
            *reinterpret_cast<uint4*>((char*)As + row * 128 + ((g ^ (row & 7)) << 4)) = v;
        }
#pragma unroll
        for (int p = 0; p < 2; ++p) {
            int gl = p * 256 + tid;
            int row = gl >> 3, g = gl & 7;
            uint4 v = *reinterpret_cast<const uint4*>(Bt + (size_t)(n0 + row) * (K / 2) + k0 / 2 + g * 4);
            *reinterpret_cast<uint4*>((char*)Bs + row * 128 + ((g ^ (row & 7)) << 4)) = v;
        }
        __syncthreads();

        bf16x8 bfrag[2][2];
#pragma unroll
        for (int kk = 0; kk < 2; ++kk)
#pragma unroll
            for (int no = 0; no < 2; ++no) {
                int row = wc * 32 + no * 16 + (lane & 15);
                int g = kk * 4 + (lane >> 4);
                bfrag[kk][no] = *reinterpret_cast<const bf16x8*>((char*)Bs + row * 128 + ((g ^ (row & 7)) << 4));
            }
#pragma unroll
        for (int mo = 0; mo < 4; ++mo) {
#pragma unroll
            for (int kk = 0; kk < 2; ++kk) {
                int row = wm * 64 + mo * 16 + (lane & 15);
                int g = kk * 4 + (lane >> 4);
                bf16x8 afrag = *reinterpret_cast<const bf16x8*>((char*)As + row * 128 + ((g ^ (row & 7)) << 4));
                acc[mo][0] = __builtin_amdgcn_mfma_f32_16x16x32_bf16(afrag, bfrag[kk][0], acc[mo][0], 0, 0, 0);
                acc[mo][1] = __builtin_amdgcn_mfma_f32_16x16x32_bf16(afrag, bfrag[kk][1], acc[mo][1], 0, 0, 0);
            }
        }
        __syncthreads();
    }
#pragma unroll
    for (int mo = 0; mo < 4; ++mo)
#pragma unroll
        for (int no = 0; no < 2; ++no) {
            int col = n0 + wc * 32 + no * 16 + (lane & 15);
            int rbase = m0 + wm * 64 + mo * 16 + (lane >> 4) * 4;
#pragma unroll
            for (int j = 0; j < 4; ++j) {
                int row = rbase + j;
                if (row < N) Yb[(size_t)row * NOUT + col] = f2bf(acc[mo][no][j]);
            }
        }
}

// ---------- attention scores from packed-bf16 features ----------
template<int H, int C>
__global__ void score_b_k(const unsigned* __restrict__ hb, const float* __restrict__ a_src,
                          const float* __restrict__ a_dst,
                          float* __restrict__ ssrc, float* __restrict__ sdst, int N) {
    int idx = blockIdx.x * blockDim.x + threadIdx.x;
    if (idx >= N * H) return;
    int n = idx / H, hh = idx % H;
    const uint4* hp = reinterpret_cast<const uint4*>(hb + (size_t)n * (H * C / 2) + hh * (C / 2));
    const float* as = a_src + hh * C;
    const float* ad = a_dst + hh * C;
    float ss = 0.f, sd = 0.f;
#pragma unroll
    for (int i = 0; i < C / 8; ++i) {
        uint4 u = hp[i];
        float v[8] = {bflo(u.x), bfhi(u.x), bflo(u.y), bfhi(u.y),
                      bflo(u.z), bfhi(u.z), bflo(u.w), bfhi(u.w)};
#pragma unroll
        for (int j = 0; j < 8; ++j) { ss += v[j] * as[i * 8 + j]; sd += v[j] * ad[i * 8 + j]; }
    }
    ssrc[idx] = ss;
    sdst[idx] = sd;
}

// ---------- fused per-node softmax + bf16 gather-aggregate + epilogue ----------
// Fast path (deg<=64): softmax one-edge-per-lane; pass 2 splits the wave into
// two 32-lane halves, each owning alternate edges with full-row 16B/8B loads.
// Edge (src, alpha) tables live in per-wave LDS -> no cross-lane ops in loop.
template<int H, int C, bool ELU, bool OUT_BF16>
__global__ void node_agg_k(const int* __restrict__ rowstart, const int* __restrict__ adj,
                           const float* __restrict__ ssrc, const float* __restrict__ sdst,
                           const unsigned* __restrict__ hb, const float* __restrict__ bias,
                           void* __restrict__ outp, int N) {
    constexpr int HC = H * C;
    constexpr int ROW_U = HC / 2;           // packed uints per row (128 or 64)
    constexpr int ULN = ROW_U / 32;         // uints per half-lane (4 or 2)
    constexpr int FPLn = ULN * 2;           // features per half-lane (8 or 4)
    int lane = threadIdx.x & 63;
    int w = threadIdx.x >> 6;
    int n = blockIdx.x * (blockDim.x >> 6) + w;
    if (n >= N) return;

    __shared__ int   s_sh[4][64];
    __shared__ float a_sh[4][64 * H];

    int r0 = rowstart[n], r1 = rowstart[n + 1];
    int deg = r1 - r0;

    float sd[H];
#pragma unroll
    for (int h = 0; h < H; ++h) sd[h] = sdst[n * H + h];

    if (deg <= 64) {
        // ---- pass 1: one edge per lane, exact softmax ----
        int s = adj[r0 + ((lane < deg) ? lane : 0)];
        float a[H];
        {
            float v[H];
            if constexpr (H == 4) {
                float4 sv = reinterpret_cast<const float4*>(ssrc)[s];
                v[0] = sv.x; v[1] = sv.y; v[2] = sv.z; v[3] = sv.w;
            } else {
                v[0] = ssrc[s];
            }
#pragma unroll
            for (int h = 0; h < H; ++h) {
                float t = v[h] + sd[h];
                t = t > 0.f ? t : 0.2f * t;
                v[h] = (lane < deg) ? t : -1e30f;
            }
            float m[H], l[H];
#pragma unroll
            for (int h = 0; h < H; ++h) m[h] = v[h];
#pragma unroll
            for (int off = 32; off; off >>= 1)
#pragma unroll
                for (int h = 0; h < H; ++h)
                    m[h] = fmaxf(m[h], __shfl_xor(m[h], off, 64));
#pragma unroll
            for (int h = 0; h < H; ++h) {
                a[h] = (lane < deg) ? __expf(v[h] - m[h]) : 0.f;
                l[h] = a[h];
            }
#pragma unroll
            for (int off = 32; off; off >>= 1)
#pragma unroll
                for (int h = 0; h < H; ++h)
                    l[h] += __shfl_xor(l[h], off, 64);
#pragma unroll
            for (int h = 0; h < H; ++h) a[h] *= __builtin_amdgcn_rcpf(l[h]);
        }
        // publish edge tables to per-wave LDS
        s_sh[w][lane] = s;
#pragma unroll
        for (int h = 0; h < H; ++h) a_sh[w][lane * H + h] = a[h];

        // ---- pass 2: half-wave per edge, full-row loads ----
        int ln = lane & 31, half = lane >> 5;
        int hA = (ln * FPLn) / C;
        const unsigned* hbl = hb + ln * ULN;
        float acc[FPLn];
#pragma unroll
        for (int f = 0; f < FPLn; ++f) acc[f] = 0.f;

        int j = half;
        for (; j + 6 < deg; j += 8) {
            int s0 = s_sh[w][j],     s1 = s_sh[w][j + 2];
            int s2 = s_sh[w][j + 4], s3 = s_sh[w][j + 6];
            float al0 = a_sh[w][j * H + hA],       al1 = a_sh[w][(j + 2) * H + hA];
            float al2 = a_sh[w][(j + 4) * H + hA], al3 = a_sh[w][(j + 6) * H + hA];
            if constexpr (ULN == 4) {
                uint4 u0 = *reinterpret_cast<const uint4*>(hbl + (size_t)s0 * ROW_U);
                uint4 u1 = *reinterpret_cast<const uint4*>(hbl + (size_t)s1 * ROW_U);
                uint4 u2 = *reinterpret_cast<const uint4*>(hbl + (size_t)s2 * ROW_U);
                uint4 u3 = *reinterpret_cast<const uint4*>(hbl + (size_t)s3 * ROW_U);
                acc[0] += al0 * bflo(u0.x); acc[1] += al0 * bfhi(u0.x);
                acc[2] += al0 * bflo(u0.y); acc[3] += al0 * bfhi(u0.y);
                acc[4] += al0 * bflo(u0.z); acc[5] += al0 * bfhi(u0.z);
                acc[6] += al0 * bflo(u0.w); acc[7] += al0 * bfhi(u0.w);
                acc[0] += al1 * bflo(u1.x); acc[1] += al1 * bfhi(u1.x);
                acc[2] += al1 * bflo(u1.y); acc[3] += al1 * bfhi(u1.y);
                acc[4] += al1 * bflo(u1.z); acc[5] += al1 * bfhi(u1.z);
                acc[6] += al1 * bflo(u1.w); acc[7] += al1 * bfhi(u1.w);
                acc[0] += al2 * bflo(u2.x); acc[1] += al2 * bfhi(u2.x);
                acc[2] += al2 * bflo(u2.y); acc[3] += al2 * bfhi(u2.y);
                acc[4] += al2 * bflo(u2.z); acc[5] += al2 * bfhi(u2.z);
                acc[6] += al2 * bflo(u2.w); acc[7] += al2 * bfhi(u2.w);
                acc[0] += al3 * bflo(u3.x); acc[1] += al3 * bfhi(u3.x);
                acc[2] += al3 * bflo(u3.y); acc[3] += al3 * bfhi(u3.y);
                acc[4] += al3 * bflo(u3.z); acc[5] += al3 * bfhi(u3.z);
                acc[6] += al3 * bflo(u3.w); acc[7] += al3 * bfhi(u3.w);
            } else {
                uint2 u0 = *reinterpret_cast<const uint2*>(hbl + (size_t)s0 * ROW_U);
                uint2 u1 = *reinterpret_cast<const uint2*>(hbl + (size_t)s1 * ROW_U);
                uint2 u2 = *reinterpret_cast<const uint2*>(hbl + (size_t)s2 * ROW_U);
                uint2 u3 = *reinterpret_cast<const uint2*>(hbl + (size_t)s3 * ROW_U);
                acc[0] += al0 * bflo(u0.x); acc[1] += al0 * bfhi(u0.x);
                acc[2] += al0 * bflo(u0.y); acc[3] += al0 * bfhi(u0.y);
                acc[0] += al1 * bflo(u1.x); acc[1] += al1 * bfhi(u1.x);
                acc[2] += al1 * bflo(u1.y); acc[3] += al1 * bfhi(u1.y);
                acc[0] += al2 * bflo(u2.x); acc[1] += al2 * bfhi(u2.x);
                acc[2] += al2 * bflo(u2.y); acc[3] += al2 * bfhi(u2.y);
                acc[0] += al3 * bflo(u3.x); acc[1] += al3 * bfhi(u3.x);
                acc[2] += al3 * bflo(u3.y); acc[3] += al3 * bfhi(u3.y);
            }
        }
        for (; j < deg; j += 2) {
            int sj = s_sh[w][j];
            float al = a_sh[w][j * H + hA];
            if constexpr (ULN == 4) {
                uint4 u = *reinterpret_cast<const uint4*>(hbl + (size_t)sj * ROW_U);
                acc[0] += al * bflo(u.x); acc[1] += al * bfhi(u.x);
                acc[2] += al * bflo(u.y); acc[3] += al * bfhi(u.y);
                acc[4] += al * bflo(u.z); acc[5] += al * bfhi(u.z);
                acc[6] += al * bflo(u.w); acc[7] += al * bfhi(u.w);
            } else {
                uint2 u = *reinterpret_cast<const uint2*>(hbl + (size_t)sj * ROW_U);
                acc[0] += al * bflo(u.x); acc[1] += al * bfhi(u.x);
                acc[2] += al * bflo(u.y); acc[3] += al * bfhi(u.y);
            }
        }
        // combine halves
#pragma unroll
        for (int f = 0; f < FPLn; ++f) acc[f] += __shfl_xor(acc[f], 32, 64);
        // epilogue (lanes 0..31 write)
#pragma unroll
        for (int f = 0; f < FPLn; ++f) {
            float v = acc[f] + bias[ln * FPLn + f];
            if (ELU) v = v > 0.f ? v : (__expf(v) - 1.f);
            acc[f] = v;
        }
        if (half == 0) {
            if constexpr (OUT_BF16) {
                unsigned* op = (unsigned*)outp + (size_t)n * ROW_U + ln * ULN;
                if constexpr (ULN == 4) {
                    uint4 u = {packbf(acc[0], acc[1]), packbf(acc[2], acc[3]),
                               packbf(acc[4], acc[5]), packbf(acc[6], acc[7])};
                    *reinterpret_cast<uint4*>(op) = u;
                } else {
                    uint2 u = {packbf(acc[0], acc[1]), packbf(acc[2], acc[3])};
                    *reinterpret_cast<uint2*>(op) = u;
                }
            } else {
                float* op = (float*)outp + (size_t)n * HC + ln * FPLn;
                if constexpr (FPLn == 4) {
                    *reinterpret_cast<float4*>(op) = make_float4(acc[0], acc[1], acc[2], acc[3]);
                } else {
#pragma unroll
                    for (int f = 0; f < FPLn; ++f) op[f] = acc[f];
                }
            }
        }
    } else {
        // ---- general path (deg > 64): online softmax + recompute ----
        constexpr int FPL = HC / 64;
        constexpr int UPL = FPL / 2;
        int hA = (lane * FPL) / C;
        float acc[FPL];
#pragma unroll
        for (int f = 0; f < FPL; ++f) acc[f] = 0.f;
        float m[H], l[H];
#pragma unroll
        for (int h = 0; h < H; ++h) { m[h] = -1e30f; l[h] = 0.f; }
        for (int e = r0 + lane; e < r1; e += 64) {
            int s = adj[e];
#pragma unroll
            for (int h = 0; h < H; ++h) {
                float v = ssrc[s * H + h] + sd[h];
                v = v > 0.f ? v : 0.2f * v;
                float mn = fmaxf(m[h], v);
                l[h] = l[h] * __expf(m[h] - mn) + __expf(v - mn);
                m[h] = mn;
            }
        }
#pragma unroll
        for (int off = 32; off; off >>= 1)
#pragma unroll
            for (int h = 0; h < H; ++h) {
                float mo = __shfl_xor(m[h], off, 64);
                float lo = __shfl_xor(l[h], off, 64);
                float mn = fmaxf(m[h], mo);
                l[h] = l[h] * __expf(m[h] - mn) + lo * __expf(mo - mn);
                m[h] = mn;
            }
        float mh = m[hA], invl = 1.f / l[hA], sdh = sd[hA];
        for (int e = r0; e < r1; ++e) {
            int s = adj[e];
            float v = ssrc[s * H + hA] + sdh;
            v = v > 0.f ? v : 0.2f * v;
            float alpha = __expf(v - mh) * invl;
            const unsigned* hp = hb + (size_t)s * ROW_U + lane * UPL;
            if constexpr (UPL == 2) {
                uint2 u = *reinterpret_cast<const uint2*>(hp);
                acc[0] += alpha * bflo(u.x); acc[1] += alpha * bfhi(u.x);
                acc[2] += alpha * bflo(u.y); acc[3] += alpha * bfhi(u.y);
            } else {
                unsigned u = *hp;
                acc[0] += alpha * bflo(u); acc[1] += alpha * bfhi(u);
            }
        }
#pragma unroll
        for (int f = 0; f < FPL; ++f) {
            float v = acc[f] + bias[lane * FPL + f];
            if (ELU) v = v > 0.f ? v : (__expf(v) - 1.f);
            acc[f] = v;
        }
        if constexpr (OUT_BF16) {
            unsigned* op = (unsigned*)outp + (size_t)n * ROW_U + lane * UPL;
            if constexpr (UPL == 2) {
                uint2 u = {packbf(acc[0], acc[1]), packbf(acc[2], acc[3])};
                *reinterpret_cast<uint2*>(op) = u;
            } else {
                *op = packbf(acc[0], acc[1]);
            }
        } else {
            float* op = (float*)outp + (size_t)n * HC + lane * FPL;
#pragma unroll
            for (int f = 0; f < FPL; ++f) op[f] = acc[f];
        }
    }
}

// ---------- launch ----------
extern "C" void kernel_launch(void* const* d_in, const int* in_sizes, int n_in,
                              void* d_out, int out_size, void* d_ws, size_t ws_size,
                              hipStream_t stream) {
    const float* x   = (const float*)d_in[0];
    const int*   ei  = (const int*)d_in[1];
    const float* W1  = (const float*)d_in[2];
    const float* as1 = (const float*)d_in[3];
    const float* ad1 = (const float*)d_in[4];
    const float* b1  = (const float*)d_in[5];
    const float* W2  = (const float*)d_in[6];
    const float* as2 = (const float*)d_in[7];
    const float* ad2 = (const float*)d_in[8];
    const float* b2  = (const float*)d_in[9];
    float* out = (float*)d_out;

    const int N  = in_sizes[0] / 128;   // 50000
    const int E  = in_sizes[1] / 2;     // 800000
    const int ET = E + N;
    const int* src = ei;
    const int* dst = ei + E;

    // workspace (4B units)
    unsigned* ws = (unsigned*)d_ws;
    unsigned* xb    = ws;                              // N*64  (x bf16)
    unsigned* h1b   = xb    + (size_t)N * 64;          // N*128
    unsigned* agg1b = h1b   + (size_t)N * 128;         // N*128
    unsigned* h2b   = agg1b + (size_t)N * 128;         // N*64
    unsigned* Wt1   = h2b   + (size_t)N * 64;          // 16384
    unsigned* Wt2   = Wt1   + 16384;                   // 16384
    float*    ssrc1 = (float*)(Wt2 + 16384);           // N*4
    float*    sdst1 = ssrc1 + (size_t)N * 4;           // N*4
    float*    ssrc2 = sdst1 + (size_t)N * 4;           // N
    float*    sdst2 = ssrc2 + N;                       // N
    int*      deg   = (int*)(sdst2 + N);               // N (reused as cursor)
    int*      rowst = deg + N;                         // N+1
    int*      bsums = rowst + N + 1;                   // 64
    int*      adj   = bsums + 64;                      // ET

    const int B = 256;
    auto blocks = [](size_t n, int b) { return (int)((n + b - 1) / b); };
    const int nscan = (N + SCAN_ELEMS - 1) / SCAN_ELEMS;

    // ---- fused prep ----
    {
        int NX2 = N * 64, NW1 = 128 * 256, NW2 = 256 * 128;
        size_t tot = (size_t)NX2 + NW1 + NW2 + N;
        prep_k<<<blocks(tot, B), B, 0, stream>>>(x, W1, W2, xb, (unsigned short*)Wt1,
                                                 (unsigned short*)Wt2, deg, NX2, NW1, NW2, N);
    }

    // ---- CSR build ----
    count_k<<<blocks(E, B), B, 0, stream>>>(dst, E, deg);
    scan1_k<<<nscan, SCAN_BLK, 0, stream>>>(deg, rowst, bsums, N);
    scan2_k<<<1, 64, 0, stream>>>(bsums, nscan);
    scan3_init_k<<<blocks(N + 1, B), B, 0, stream>>>(rowst, bsums, adj, deg, N, ET);
    scatter_k<<<blocks(E, B), B, 0, stream>>>(src, dst, E, deg, adj);

    // ---- layer 1 ----
    {
        dim3 g((N + 127) / 128, 256 / 64);
        gemm_mfma_k<128, 256><<<g, 256, 0, stream>>>(xb, (const unsigned*)Wt1, (unsigned short*)h1b, N);
    }
    score_b_k<4, 64><<<blocks((size_t)N * 4, B), B, 0, stream>>>(h1b, as1, ad1, ssrc1, sdst1, N);
    node_agg_k<4, 64, true, true><<<(N + 3) / 4, 256, 0, stream>>>(rowst, adj, ssrc1, sdst1, h1b, b1, agg1b, N);

    // ---- layer 2 ----
    {
        dim3 g((N + 127) / 128, 128 / 64);
        gemm_mfma_k<256, 128><<<g, 256, 0, stream>>>(agg1b, (const unsigned*)Wt2, (unsigned short*)h2b, N);
    }
    score_b_k<1, 128><<<blocks(N, B), B, 0, stream>>>(h2b, as2, ad2, ssrc2, sdst2, N);
    node_agg_k<1, 128, false, false><<<(N + 3) / 4, 256, 0, stream>>>(rowst, adj, ssrc2, sdst2, h2b, b2, out, N);
}

// Round 8
// 262.374 us; speedup vs baseline: 1.0485x; 1.0485x over previous
//
#include <hip/hip_runtime.h>
#include <cmath>

typedef __attribute__((ext_vector_type(8))) short bf16x8;
typedef __attribute__((ext_vector_type(4))) float f32x4;

// ---------- bf16 pack/unpack ----------
static __device__ __forceinline__ unsigned short f2bf(float f) {
    unsigned u = __float_as_uint(f);
    unsigned r = (u + 0x7fffu + ((u >> 16) & 1u)) >> 16;   // RNE
    return (unsigned short)r;
}
static __device__ __forceinline__ unsigned packbf(float a, float b) {
    return (unsigned)f2bf(a) | ((unsigned)f2bf(b) << 16);
}
static __device__ __forceinline__ float bflo(unsigned u) { return __uint_as_float(u << 16); }
static __device__ __forceinline__ float bfhi(unsigned u) { return __uint_as_float(u & 0xffff0000u); }

// ---------- fused prep: x->bf16, W1/W2 transpose->bf16, edge count ----------
__global__ void prep_k(const float* __restrict__ x, const float* __restrict__ W1,
                       const float* __restrict__ W2, const int* __restrict__ dst,
                       unsigned* __restrict__ xb,
                       unsigned short* __restrict__ Wt1, unsigned short* __restrict__ Wt2,
                       int* __restrict__ deg, int NX2, int NW1, int NW2, int E) {
    int i = blockIdx.x * blockDim.x + threadIdx.x;
    if (i < NX2) {
        float2 v = reinterpret_cast<const float2*>(x)[i];
        xb[i] = packbf(v.x, v.y);
        return;
    }
    i -= NX2;
    if (i < NW1) { int nn = i / 128, k = i % 128; Wt1[i] = f2bf(W1[(size_t)k * 256 + nn]); return; }
    i -= NW1;
    if (i < NW2) { int nn = i / 256, k = i % 256; Wt2[i] = f2bf(W2[(size_t)k * 128 + nn]); return; }
    i -= NW2;
    if (i < E) atomicAdd(&deg[dst[i]], 1);
}

#define SCAN_BLK 256
#define SCAN_ELEMS 2048

// scan1: deg[i]+1 (implicit self-loop)
__global__ void scan1_k(const int* __restrict__ deg, int* __restrict__ rowstart,
                        int* __restrict__ bsums, int N) {
    __shared__ int sh[SCAN_BLK];
    int t = threadIdx.x;
    int base = blockIdx.x * SCAN_ELEMS + t * 8;
    int vals[8];
    int sum = 0;
#pragma unroll
    for (int i = 0; i < 8; ++i) {
        int idx = base + i;
        vals[i] = (idx < N) ? (deg[idx] + 1) : 0;
        sum += vals[i];
    }
    sh[t] = sum;
    __syncthreads();
    for (int off = 1; off < SCAN_BLK; off <<= 1) {
        int v = (t >= off) ? sh[t - off] : 0;
        __syncthreads();
        sh[t] += v;
        __syncthreads();
    }
    int run = sh[t] - sum;
    if (t == SCAN_BLK - 1) bsums[blockIdx.x] = sh[t];
#pragma unroll
    for (int i = 0; i < 8; ++i) {
        int idx = base + i;
        if (idx < N) rowstart[idx] = run;
        run += vals[i];
    }
}
// wave-parallel exclusive scan of block sums (nb <= 64)
__global__ void scan2_k(int* __restrict__ bsums, int nb) {
    int lane = threadIdx.x;
    int own = (lane < nb) ? bsums[lane] : 0;
    int v = own;
    for (int off = 1; off < 64; off <<= 1) {
        int t = __shfl_up(v, off, 64);
        if (lane >= off) v += t;
    }
    if (lane < nb) bsums[lane] = v - own;
}
// scan3 + initadj fused
__global__ void scan3_init_k(int* __restrict__ rowstart, const int* __restrict__ bsums,
                             int* __restrict__ adj, int* __restrict__ cursor, int N, int total) {
    int i = blockIdx.x * blockDim.x + threadIdx.x;
    if (i < N) {
        int r = rowstart[i] + bsums[i / SCAN_ELEMS];
        rowstart[i] = r;
        adj[r] = i;          // self-loop first
        cursor[i] = r + 1;
    } else if (i == N) {
        rowstart[N] = total;
    }
}
__global__ void scatter_k(const int* __restrict__ src, const int* __restrict__ dst, int E,
                          int* __restrict__ cursor, int* __restrict__ adj) {
    int e = blockIdx.x * blockDim.x + threadIdx.x;
    if (e >= E) return;
    int pos = atomicAdd(&cursor[dst[e]], 1);
    adj[pos] = src[e];
}

// ---------- MFMA GEMM: Yb[N,NOUT](bf16) = Ab[N,K](bf16) @ Wt[NOUT,K](bf16)^T ----------
template<int K, int NOUT>
__global__ __launch_bounds__(256) void gemm_mfma_k(const unsigned* __restrict__ Ab,
                                                   const unsigned* __restrict__ Bt,
                                                   unsigned short* __restrict__ Yb, int N) {
    __shared__ unsigned short As[128 * 64];
    __shared__ unsigned short Bs[64 * 64];
    int tid = threadIdx.x;
    int lane = tid & 63, wid = tid >> 6;
    int wm = wid >> 1, wc = wid & 1;
    int m0 = blockIdx.x * 128;
    int n0 = blockIdx.y * 64;

    f32x4 acc[4][2] = {};

    for (int k0 = 0; k0 < K; k0 += 64) {
#pragma unroll
        for (int p = 0; p < 4; ++p) {
            int gl = p * 256 + tid;
            int row = gl >> 3, g = gl & 7;
            int grow = m0 + row; if (grow >= N) grow = N - 1;
            uint4 v = *reinterpret_cast<const uint4*>(Ab + (size_t)grow * (K / 2) + k0 / 2 + g * 4);
            *reinterpret_cast<uint4*>((char*)As + row * 128 + ((g ^ (row & 7)) << 4)) = v;
        }
#pragma unroll
        for (int p = 0; p < 2; ++p) {
            int gl = p * 256 + tid;
            int row = gl >> 3, g = gl & 7;
            uint4 v = *reinterpret_cast<const uint4*>(Bt + (size_t)(n0 + row) * (K / 2) + k0 / 2 + g * 4);
            *reinterpret_cast<uint4*>((char*)Bs + row * 128 + ((g ^ (row & 7)) << 4)) = v;
        }
        __syncthreads();

        bf16x8 bfrag[2][2];
#pragma unroll
        for (int kk = 0; kk < 2; ++kk)
#pragma unroll
            for (int no = 0; no < 2; ++no) {
                int row = wc * 32 + no * 16 + (lane & 15);
                int g = kk * 4 + (lane >> 4);
                bfrag[kk][no] = *reinterpret_cast<const bf16x8*>((char*)Bs + row * 128 + ((g ^ (row & 7)) << 4));
            }
#pragma unroll
        for (int mo = 0; mo < 4; ++mo) {
#pragma unroll
            for (int kk = 0; kk < 2; ++kk) {
                int row = wm * 64 + mo * 16 + (lane & 15);
                int g = kk * 4 + (lane >> 4);
                bf16x8 afrag = *reinterpret_cast<const bf16x8*>((char*)As + row * 128 + ((g ^ (row & 7)) << 4));
                acc[mo][0] = __builtin_amdgcn_mfma_f32_16x16x32_bf16(afrag, bfrag[kk][0], acc[mo][0], 0, 0, 0);
                acc[mo][1] = __builtin_amdgcn_mfma_f32_16x16x32_bf16(afrag, bfrag[kk][1], acc[mo][1], 0, 0, 0);
            }
        }
        __syncthreads();
    }
#pragma unroll
    for (int mo = 0; mo < 4; ++mo)
#pragma unroll
        for (int no = 0; no < 2; ++no) {
            int col = n0 + wc * 32 + no * 16 + (lane & 15);
            int rbase = m0 + wm * 64 + mo * 16 + (lane >> 4) * 4;
#pragma unroll
            for (int j = 0; j < 4; ++j) {
                int row = rbase + j;
                if (row < N) Yb[(size_t)row * NOUT + col] = f2bf(acc[mo][no][j]);
            }
        }
}

// ---------- attention scores from packed-bf16 features ----------
template<int H, int C>
__global__ void score_b_k(const unsigned* __restrict__ hb, const float* __restrict__ a_src,
                          const float* __restrict__ a_dst,
                          float* __restrict__ ssrc, float* __restrict__ sdst, int N) {
    int idx = blockIdx.x * blockDim.x + threadIdx.x;
    if (idx >= N * H) return;
    int n = idx / H, hh = idx % H;
    const uint4* hp = reinterpret_cast<const uint4*>(hb + (size_t)n * (H * C / 2) + hh * (C / 2));
    const float* as = a_src + hh * C;
    const float* ad = a_dst + hh * C;
    float ss = 0.f, sd = 0.f;
#pragma unroll
    for (int i = 0; i < C / 8; ++i) {
        uint4 u = hp[i];
        float v[8] = {bflo(u.x), bfhi(u.x), bflo(u.y), bfhi(u.y),
                      bflo(u.z), bfhi(u.z), bflo(u.w), bfhi(u.w)};
#pragma unroll
        for (int j = 0; j < 8; ++j) { ss += v[j] * as[i * 8 + j]; sd += v[j] * ad[i * 8 + j]; }
    }
    ssrc[idx] = ss;
    sdst[idx] = sd;
}

// ---------- fused per-node softmax + bf16 gather-aggregate + epilogue ----------
// Fast path (deg<=64): softmax WITHOUT max-subtract (scores are O(8), f32-safe),
// sum butterfly skips off=32 when deg<=32. Pass 2: GRP lanes per edge (16B/lane
// uint4 covers the whole row), NGRP=64/GRP edges concurrent, unroll 4.
template<int H, int C, int GRP, bool ELU, bool OUT_BF16>
__global__ void node_agg_k(const int* __restrict__ rowstart, const int* __restrict__ adj,
                           const float* __restrict__ ssrc, const float* __restrict__ sdst,
                           const unsigned* __restrict__ hb, const float* __restrict__ bias,
                           void* __restrict__ outp, int N) {
    constexpr int HC = H * C;
    constexpr int ROW_U = HC / 2;           // packed uints per row
    constexpr int ULN = ROW_U / GRP;        // uints per lane (4 for both layers)
    constexpr int FPLn = ULN * 2;           // features per lane
    constexpr int NGRP = 64 / GRP;          // edges in parallel per wave
    int lane = threadIdx.x & 63;
    int w = threadIdx.x >> 6;
    int n = blockIdx.x * (blockDim.x >> 6) + w;
    if (n >= N) return;

    __shared__ int   s_sh[4][64];
    __shared__ float a_sh[4][64 * H];

    int r0 = rowstart[n], r1 = rowstart[n + 1];
    int deg = r1 - r0;

    float sd[H];
#pragma unroll
    for (int h = 0; h < H; ++h) sd[h] = sdst[n * H + h];

    if (deg <= 64) {
        // ---- pass 1: one edge per lane; alpha = exp(v)/sum(exp(v)) ----
        int s = adj[r0 + ((lane < deg) ? lane : 0)];
        float a[H], l[H];
        {
            float v[H];
            if constexpr (H == 4) {
                float4 sv = reinterpret_cast<const float4*>(ssrc)[s];
                v[0] = sv.x; v[1] = sv.y; v[2] = sv.z; v[3] = sv.w;
            } else {
                v[0] = ssrc[s];
            }
#pragma unroll
            for (int h = 0; h < H; ++h) {
                float t = v[h] + sd[h];
                t = t > 0.f ? t : 0.2f * t;
                a[h] = (lane < deg) ? __expf(t) : 0.f;
                l[h] = a[h];
            }
            if (deg > 32)
#pragma unroll
                for (int h = 0; h < H; ++h) l[h] += __shfl_xor(l[h], 32, 64);
#pragma unroll
            for (int off = 16; off; off >>= 1)
#pragma unroll
                for (int h = 0; h < H; ++h) l[h] += __shfl_xor(l[h], off, 64);
#pragma unroll
            for (int h = 0; h < H; ++h) a[h] *= __builtin_amdgcn_rcpf(l[h]);
        }
        s_sh[w][lane] = s;
#pragma unroll
        for (int h = 0; h < H; ++h) a_sh[w][lane * H + h] = a[h];

        // ---- pass 2: GRP-lane groups, full-row uint4 loads, 4-deep ----
        int g = lane / GRP, ln = lane % GRP;
        int hA = (ln * FPLn) / C;
        const unsigned* hbl = hb + ln * ULN;
        float acc[FPLn];
#pragma unroll
        for (int f = 0; f < FPLn; ++f) acc[f] = 0.f;

        int j = g;
        for (; j + 3 * NGRP < deg; j += 4 * NGRP) {
            int s0 = s_sh[w][j],            s1 = s_sh[w][j + NGRP];
            int s2 = s_sh[w][j + 2 * NGRP], s3 = s_sh[w][j + 3 * NGRP];
            float al0 = a_sh[w][j * H + hA],            al1 = a_sh[w][(j + NGRP) * H + hA];
            float al2 = a_sh[w][(j + 2 * NGRP) * H + hA], al3 = a_sh[w][(j + 3 * NGRP) * H + hA];
            uint4 u0 = *reinterpret_cast<const uint4*>(hbl + (size_t)s0 * ROW_U);
            uint4 u1 = *reinterpret_cast<const uint4*>(hbl + (size_t)s1 * ROW_U);
            uint4 u2 = *reinterpret_cast<const uint4*>(hbl + (size_t)s2 * ROW_U);
            uint4 u3 = *reinterpret_cast<const uint4*>(hbl + (size_t)s3 * ROW_U);
            acc[0] += al0 * bflo(u0.x); acc[1] += al0 * bfhi(u0.x);
            acc[2] += al0 * bflo(u0.y); acc[3] += al0 * bfhi(u0.y);
            acc[4] += al0 * bflo(u0.z); acc[5] += al0 * bfhi(u0.z);
            acc[6] += al0 * bflo(u0.w); acc[7] += al0 * bfhi(u0.w);
            acc[0] += al1 * bflo(u1.x); acc[1] += al1 * bfhi(u1.x);
            acc[2] += al1 * bflo(u1.y); acc[3] += al1 * bfhi(u1.y);
            acc[4] += al1 * bflo(u1.z); acc[5] += al1 * bfhi(u1.z);
            acc[6] += al1 * bflo(u1.w); acc[7] += al1 * bfhi(u1.w);
            acc[0] += al2 * bflo(u2.x); acc[1] += al2 * bfhi(u2.x);
            acc[2] += al2 * bflo(u2.y); acc[3] += al2 * bfhi(u2.y);
            acc[4] += al2 * bflo(u2.z); acc[5] += al2 * bfhi(u2.z);
            acc[6] += al2 * bflo(u2.w); acc[7] += al2 * bfhi(u2.w);
            acc[0] += al3 * bflo(u3.x); acc[1] += al3 * bfhi(u3.x);
            acc[2] += al3 * bflo(u3.y); acc[3] += al3 * bfhi(u3.y);
            acc[4] += al3 * bflo(u3.z); acc[5] += al3 * bfhi(u3.z);
            acc[6] += al3 * bflo(u3.w); acc[7] += al3 * bfhi(u3.w);
        }
        for (; j < deg; j += NGRP) {
            int sj = s_sh[w][j];
            float al = a_sh[w][j * H + hA];
            uint4 u = *reinterpret_cast<const uint4*>(hbl + (size_t)sj * ROW_U);
            acc[0] += al * bflo(u.x); acc[1] += al * bfhi(u.x);
            acc[2] += al * bflo(u.y); acc[3] += al * bfhi(u.y);
            acc[4] += al * bflo(u.z); acc[5] += al * bfhi(u.z);
            acc[6] += al * bflo(u.w); acc[7] += al * bfhi(u.w);
        }
        // combine groups
#pragma unroll
        for (int off = GRP; off < 64; off <<= 1)
#pragma unroll
            for (int f = 0; f < FPLn; ++f) acc[f] += __shfl_xor(acc[f], off, 64);
        // epilogue
#pragma unroll
        for (int f = 0; f < FPLn; ++f) {
            float v = acc[f] + bias[ln * FPLn + f];
            if (ELU) v = v > 0.f ? v : (__expf(v) - 1.f);
            acc[f] = v;
        }
        if (g == 0) {
            if constexpr (OUT_BF16) {
                unsigned* op = (unsigned*)outp + (size_t)n * ROW_U + ln * ULN;
                uint4 u = {packbf(acc[0], acc[1]), packbf(acc[2], acc[3]),
                           packbf(acc[4], acc[5]), packbf(acc[6], acc[7])};
                *reinterpret_cast<uint4*>(op) = u;
            } else {
                float* op = (float*)outp + (size_t)n * HC + ln * FPLn;
                *reinterpret_cast<float4*>(op) = make_float4(acc[0], acc[1], acc[2], acc[3]);
                *reinterpret_cast<float4*>(op + 4) = make_float4(acc[4], acc[5], acc[6], acc[7]);
            }
        }
    } else {
        // ---- general path (deg > 64): online softmax + recompute ----
        constexpr int FPL = HC / 64;
        constexpr int UPL = FPL / 2;
        int hA = (lane * FPL) / C;
        float acc[FPL];
#pragma unroll
        for (int f = 0; f < FPL; ++f) acc[f] = 0.f;
        float m[H], l[H];
#pragma unroll
        for (int h = 0; h < H; ++h) { m[h] = -1e30f; l[h] = 0.f; }
        for (int e = r0 + lane; e < r1; e += 64) {
            int s = adj[e];
#pragma unroll
            for (int h = 0; h < H; ++h) {
                float v = ssrc[s * H + h] + sd[h];
                v = v > 0.f ? v : 0.2f * v;
                float mn = fmaxf(m[h], v);
                l[h] = l[h] * __expf(m[h] - mn) + __expf(v - mn);
                m[h] = mn;
            }
        }
#pragma unroll
        for (int off = 32; off; off >>= 1)
#pragma unroll
            for (int h = 0; h < H; ++h) {
                float mo = __shfl_xor(m[h], off, 64);
                float lo = __shfl_xor(l[h], off, 64);
                float mn = fmaxf(m[h], mo);
                l[h] = l[h] * __expf(m[h] - mn) + lo * __expf(mo - mn);
                m[h] = mn;
            }
        float mh = m[hA], invl = 1.f / l[hA], sdh = sd[hA];
        for (int e = r0; e < r1; ++e) {
            int s = adj[e];
            float v = ssrc[s * H + hA] + sdh;
            v = v > 0.f ? v : 0.2f * v;
            float alpha = __expf(v - mh) * invl;
            const unsigned* hp = hb + (size_t)s * ROW_U + lane * UPL;
            if constexpr (UPL == 2) {
                uint2 u = *reinterpret_cast<const uint2*>(hp);
                acc[0] += alpha * bflo(u.x); acc[1] += alpha * bfhi(u.x);
                acc[2] += alpha * bflo(u.y); acc[3] += alpha * bfhi(u.y);
            } else {
                unsigned u = *hp;
                acc[0] += alpha * bflo(u); acc[1] += alpha * bfhi(u);
            }
        }
#pragma unroll
        for (int f = 0; f < FPL; ++f) {
            float v = acc[f] + bias[lane * FPL + f];
            if (ELU) v = v > 0.f ? v : (__expf(v) - 1.f);
            acc[f] = v;
        }
        if constexpr (OUT_BF16) {
            unsigned* op = (unsigned*)outp + (size_t)n * ROW_U + lane * UPL;
            if constexpr (UPL == 2) {
                uint2 u = {packbf(acc[0], acc[1]), packbf(acc[2], acc[3])};
                *reinterpret_cast<uint2*>(op) = u;
            } else {
                *op = packbf(acc[0], acc[1]);
            }
        } else {
            float* op = (float*)outp + (size_t)n * HC + lane * FPL;
#pragma unroll
            for (int f = 0; f < FPL; ++f) op[f] = acc[f];
        }
    }
}

// ---------- launch ----------
extern "C" void kernel_launch(void* const* d_in, const int* in_sizes, int n_in,
                              void* d_out, int out_size, void* d_ws, size_t ws_size,
                              hipStream_t stream) {
    const float* x   = (const float*)d_in[0];
    const int*   ei  = (const int*)d_in[1];
    const float* W1  = (const float*)d_in[2];
    const float* as1 = (const float*)d_in[3];
    const float* ad1 = (const float*)d_in[4];
    const float* b1  = (const float*)d_in[5];
    const float* W2  = (const float*)d_in[6];
    const float* as2 = (const float*)d_in[7];
    const float* ad2 = (const float*)d_in[8];
    const float* b2  = (const float*)d_in[9];
    float* out = (float*)d_out;

    const int N  = in_sizes[0] / 128;   // 50000
    const int E  = in_sizes[1] / 2;     // 800000
    const int ET = E + N;
    const int* src = ei;
    const int* dst = ei + E;

    // workspace (4B units)
    unsigned* ws = (unsigned*)d_ws;
    unsigned* xb    = ws;                              // N*64  (x bf16)
    unsigned* h1b   = xb    + (size_t)N * 64;          // N*128
    unsigned* agg1b = h1b   + (size_t)N * 128;         // N*128
    unsigned* h2b   = agg1b + (size_t)N * 128;         // N*64
    unsigned* Wt1   = h2b   + (size_t)N * 64;          // 16384
    unsigned* Wt2   = Wt1   + 16384;                   // 16384
    float*    ssrc1 = (float*)(Wt2 + 16384);           // N*4
    float*    sdst1 = ssrc1 + (size_t)N * 4;           // N*4
    float*    ssrc2 = sdst1 + (size_t)N * 4;           // N
    float*    sdst2 = ssrc2 + N;                       // N
    int*      deg   = (int*)(sdst2 + N);               // N (reused as cursor)
    int*      rowst = deg + N;                         // N+1
    int*      bsums = rowst + N + 1;                   // 64
    int*      adj   = bsums + 64;                      // ET

    const int B = 256;
    auto blocks = [](size_t n, int b) { return (int)((n + b - 1) / b); };
    const int nscan = (N + SCAN_ELEMS - 1) / SCAN_ELEMS;

    // ---- fused prep (deg zeroed first; prep also counts edges) ----
    hipMemsetAsync(deg, 0, (size_t)N * 4, stream);
    {
        int NX2 = N * 64, NW1 = 128 * 256, NW2 = 256 * 128;
        size_t tot = (size_t)NX2 + NW1 + NW2 + E;
        prep_k<<<blocks(tot, B), B, 0, stream>>>(x, W1, W2, dst, xb, (unsigned short*)Wt1,
                                                 (unsigned short*)Wt2, deg, NX2, NW1, NW2, E);
    }

    // ---- CSR build ----
    scan1_k<<<nscan, SCAN_BLK, 0, stream>>>(deg, rowst, bsums, N);
    scan2_k<<<1, 64, 0, stream>>>(bsums, nscan);
    scan3_init_k<<<blocks(N + 1, B), B, 0, stream>>>(rowst, bsums, adj, deg, N, ET);
    scatter_k<<<blocks(E, B), B, 0, stream>>>(src, dst, E, deg, adj);

    // ---- layer 1 ----
    {
        dim3 g((N + 127) / 128, 256 / 64);
        gemm_mfma_k<128, 256><<<g, 256, 0, stream>>>(xb, (const unsigned*)Wt1, (unsigned short*)h1b, N);
    }
    score_b_k<4, 64><<<blocks((size_t)N * 4, B), B, 0, stream>>>(h1b, as1, ad1, ssrc1, sdst1, N);
    node_agg_k<4, 64, 32, true, true><<<(N + 3) / 4, 256, 0, stream>>>(rowst, adj, ssrc1, sdst1, h1b, b1, agg1b, N);

    // ---- layer 2 ----
    {
        dim3 g((N + 127) / 128, 128 / 64);
        gemm_mfma_k<256, 128><<<g, 256, 0, stream>>>(agg1b, (const unsigned*)Wt2, (unsigned short*)h2b, N);
    }
    score_b_k<1, 128><<<blocks(N, B), B, 0, stream>>>(h2b, as2, ad2, ssrc2, sdst2, N);
    node_agg_k<1, 128, 16, false, false><<<(N + 3) / 4, 256, 0, stream>>>(rowst, adj, ssrc2, sdst2, h2b, b2, out, N);
}

// Round 9
// 255.150 us; speedup vs baseline: 1.0781x; 1.0283x over previous
//
#include <hip/hip_runtime.h>
#include <cmath>

typedef __attribute__((ext_vector_type(8))) short bf16x8;
typedef __attribute__((ext_vector_type(4))) float f32x4;

// ---------- bf16 pack/unpack ----------
static __device__ __forceinline__ unsigned short f2bf(float f) {
    unsigned u = __float_as_uint(f);
    unsigned r = (u + 0x7fffu + ((u >> 16) & 1u)) >> 16;   // RNE
    return (unsigned short)r;
}
static __device__ __forceinline__ unsigned packbf(float a, float b) {
    return (unsigned)f2bf(a) | ((unsigned)f2bf(b) << 16);
}
static __device__ __forceinline__ float bflo(unsigned u) { return __uint_as_float(u << 16); }
static __device__ __forceinline__ float bfhi(unsigned u) { return __uint_as_float(u & 0xffff0000u); }

// ---------- fused prep: x->bf16, W1/W2 transpose->bf16, edge count ----------
__global__ void prep_k(const float* __restrict__ x, const float* __restrict__ W1,
                       const float* __restrict__ W2, const int* __restrict__ dst,
                       unsigned* __restrict__ xb,
                       unsigned short* __restrict__ Wt1, unsigned short* __restrict__ Wt2,
                       int* __restrict__ deg, int NX2, int NW1, int NW2, int E) {
    int i = blockIdx.x * blockDim.x + threadIdx.x;
    if (i < NX2) {
        float2 v = reinterpret_cast<const float2*>(x)[i];
        xb[i] = packbf(v.x, v.y);
        return;
    }
    i -= NX2;
    if (i < NW1) { int nn = i / 128, k = i % 128; Wt1[i] = f2bf(W1[(size_t)k * 256 + nn]); return; }
    i -= NW1;
    if (i < NW2) { int nn = i / 256, k = i % 256; Wt2[i] = f2bf(W2[(size_t)k * 128 + nn]); return; }
    i -= NW2;
    if (i < E) atomicAdd(&deg[dst[i]], 1);
}

#define SCAN_BLK 256
#define SCAN_ELEMS 2048

// scan1: deg[i]+1 (implicit self-loop)
__global__ void scan1_k(const int* __restrict__ deg, int* __restrict__ rowstart,
                        int* __restrict__ bsums, int N) {
    __shared__ int sh[SCAN_BLK];
    int t = threadIdx.x;
    int base = blockIdx.x * SCAN_ELEMS + t * 8;
    int vals[8];
    int sum = 0;
#pragma unroll
    for (int i = 0; i < 8; ++i) {
        int idx = base + i;
        vals[i] = (idx < N) ? (deg[idx] + 1) : 0;
        sum += vals[i];
    }
    sh[t] = sum;
    __syncthreads();
    for (int off = 1; off < SCAN_BLK; off <<= 1) {
        int v = (t >= off) ? sh[t - off] : 0;
        __syncthreads();
        sh[t] += v;
        __syncthreads();
    }
    int run = sh[t] - sum;
    if (t == SCAN_BLK - 1) bsums[blockIdx.x] = sh[t];
#pragma unroll
    for (int i = 0; i < 8; ++i) {
        int idx = base + i;
        if (idx < N) rowstart[idx] = run;
        run += vals[i];
    }
}
// wave-parallel exclusive scan of block sums (nb <= 64)
__global__ void scan2_k(int* __restrict__ bsums, int nb) {
    int lane = threadIdx.x;
    int own = (lane < nb) ? bsums[lane] : 0;
    int v = own;
    for (int off = 1; off < 64; off <<= 1) {
        int t = __shfl_up(v, off, 64);
        if (lane >= off) v += t;
    }
    if (lane < nb) bsums[lane] = v - own;
}
// scan3 + initadj fused
__global__ void scan3_init_k(int* __restrict__ rowstart, const int* __restrict__ bsums,
                             int* __restrict__ adj, int* __restrict__ cursor, int N, int total) {
    int i = blockIdx.x * blockDim.x + threadIdx.x;
    if (i < N) {
        int r = rowstart[i] + bsums[i / SCAN_ELEMS];
        rowstart[i] = r;
        adj[r] = i;          // self-loop first
        cursor[i] = r + 1;
    } else if (i == N) {
        rowstart[N] = total;
    }
}
__global__ void scatter_k(const int* __restrict__ src, const int* __restrict__ dst, int E,
                          int* __restrict__ cursor, int* __restrict__ adj) {
    int e = blockIdx.x * blockDim.x + threadIdx.x;
    if (e >= E) return;
    int pos = atomicAdd(&cursor[dst[e]], 1);
    adj[pos] = src[e];
}

// ---------- MFMA GEMM: Yb[N,NOUT](bf16) = Ab[N,K](bf16) @ Wt[NOUT,K](bf16)^T ----------
template<int K, int NOUT>
__global__ __launch_bounds__(256) void gemm_mfma_k(const unsigned* __restrict__ Ab,
                                                   const unsigned* __restrict__ Bt,
                                                   unsigned short* __restrict__ Yb, int N) {
    __shared__ unsigned short As[128 * 64];
    __shared__ unsigned short Bs[64 * 64];
    int tid = threadIdx.x;
    int lane = tid & 63, wid = tid >> 6;
    int wm = wid >> 1, wc = wid & 1;
    int m0 = blockIdx.x * 128;
    int n0 = blockIdx.y * 64;

    f32x4 acc[4][2] = {};

    for (int k0 = 0; k0 < K; k0 += 64) {
#pragma unroll
        for (int p = 0; p < 4; ++p) {
            int gl = p * 256 + tid;
            int row = gl >> 3, g = gl & 7;
            int grow = m0 + row; if (grow >= N) grow = N - 1;
            uint4 v = *reinterpret_cast<const uint4*>(Ab + (size_t)grow * (K / 2) + k0 / 2 + g * 4);
            *reinterpret_cast<uint4*>((char*)As + row * 128 + ((g ^ (row & 7)) << 4)) = v;
        }
#pragma unroll
        for (int p = 0; p < 2; ++p) {
            int gl = p * 256 + tid;
            int row = gl >> 3, g = gl & 7;
            uint4 v = *reinterpret_cast<const uint4*>(Bt + (size_t)(n0 + row) * (K / 2) + k0 / 2 + g * 4);
            *reinterpret_cast<uint4*>((char*)Bs + row * 128 + ((g ^ (row & 7)) << 4)) = v;
        }
        __syncthreads();

        bf16x8 bfrag[2][2];
#pragma unroll
        for (int kk = 0; kk < 2; ++kk)
#pragma unroll
            for (int no = 0; no < 2; ++no) {
                int row = wc * 32 + no * 16 + (lane & 15);
                int g = kk * 4 + (lane >> 4);
                bfrag[kk][no] = *reinterpret_cast<const bf16x8*>((char*)Bs + row * 128 + ((g ^ (row & 7)) << 4));
            }
#pragma unroll
        for (int mo = 0; mo < 4; ++mo) {
#pragma unroll
            for (int kk = 0; kk < 2; ++kk) {
                int row = wm * 64 + mo * 16 + (lane & 15);
                int g = kk * 4 + (lane >> 4);
                bf16x8 afrag = *reinterpret_cast<const bf16x8*>((char*)As + row * 128 + ((g ^ (row & 7)) << 4));
                acc[mo][0] = __builtin_amdgcn_mfma_f32_16x16x32_bf16(afrag, bfrag[kk][0], acc[mo][0], 0, 0, 0);
                acc[mo][1] = __builtin_amdgcn_mfma_f32_16x16x32_bf16(afrag, bfrag[kk][1], acc[mo][1], 0, 0, 0);
            }
        }
        __syncthreads();
    }
#pragma unroll
    for (int mo = 0; mo < 4; ++mo)
#pragma unroll
        for (int no = 0; no < 2; ++no) {
            int col = n0 + wc * 32 + no * 16 + (lane & 15);
            int rbase = m0 + wm * 64 + mo * 16 + (lane >> 4) * 4;
#pragma unroll
            for (int j = 0; j < 4; ++j) {
                int row = rbase + j;
                if (row < N) Yb[(size_t)row * NOUT + col] = f2bf(acc[mo][no][j]);
            }
        }
}

// ---------- attention scores from packed-bf16 features ----------
template<int H, int C>
__global__ void score_b_k(const unsigned* __restrict__ hb, const float* __restrict__ a_src,
                          const float* __restrict__ a_dst,
                          float* __restrict__ ssrc, float* __restrict__ sdst, int N) {
    int idx = blockIdx.x * blockDim.x + threadIdx.x;
    if (idx >= N * H) return;
    int n = idx / H, hh = idx % H;
    const uint4* hp = reinterpret_cast<const uint4*>(hb + (size_t)n * (H * C / 2) + hh * (C / 2));
    const float* as = a_src + hh * C;
    const float* ad = a_dst + hh * C;
    float ss = 0.f, sd = 0.f;
#pragma unroll
    for (int i = 0; i < C / 8; ++i) {
        uint4 u = hp[i];
        float v[8] = {bflo(u.x), bfhi(u.x), bflo(u.y), bfhi(u.y),
                      bflo(u.z), bfhi(u.z), bflo(u.w), bfhi(u.w)};
#pragma unroll
        for (int j = 0; j < 8; ++j) { ss += v[j] * as[i * 8 + j]; sd += v[j] * ad[i * 8 + j]; }
    }
    ssrc[idx] = ss;
    sdst[idx] = sd;
}

// ---------- fused per-node softmax + bf16 gather-aggregate + epilogue ----------
// One GRP-lane group per node: GRP lanes cover the whole feature row (16B/lane),
// each wave carries 64/GRP independent nodes. Softmax without max-subtract
// (scores O(10), f32-safe); alpha stored UNNORMALIZED in per-group LDS tables;
// 1/l folded into the epilogue so pass 2 never waits on the sum butterfly.
// No cross-group combine: each lane accumulates every edge for its own features.
template<int H, int C, int GRP, bool ELU, bool OUT_BF16>
__global__ void node_agg_k(const int* __restrict__ rowstart, const int* __restrict__ adj,
                           const float* __restrict__ ssrc, const float* __restrict__ sdst,
                           const unsigned* __restrict__ hb, const float* __restrict__ bias,
                           void* __restrict__ outp, int N) {
    constexpr int HC = H * C;
    constexpr int ROW_U = HC / 2;           // packed uints per row
    constexpr int ULN = ROW_U / GRP;        // uints per lane (=4: 16B)
    constexpr int FPLn = ULN * 2;           // features per lane (=8)
    constexpr int NG = 64 / GRP;            // groups (nodes) per wave
    constexpr int NGB = 4 * NG;             // groups per block (4 waves)
    int lane = threadIdx.x & 63;
    int w = threadIdx.x >> 6;
    int g = lane / GRP, ln = lane % GRP;
    int gid = w * NG + g;
    int n = blockIdx.x * NGB + gid;
    if (n >= N) return;

    __shared__ int   s_tab[NGB][64];
    __shared__ float a_tab[NGB][64 * H];

    int r0 = rowstart[n], r1 = rowstart[n + 1];
    int deg = r1 - r0;

    float sd[H];
#pragma unroll
    for (int h = 0; h < H; ++h) sd[h] = sdst[n * H + h];

    int hA = (ln * FPLn) / C;
    const unsigned* hbl = hb + ln * ULN;
    float acc[FPLn];
#pragma unroll
    for (int f = 0; f < FPLn; ++f) acc[f] = 0.f;
    float l[H];
#pragma unroll
    for (int h = 0; h < H; ++h) l[h] = 0.f;

    if (deg <= 64) {
        // ---- pass 1: strided chunks of GRP edges; fill (s, alpha) tables ----
        for (int base = 0; base < deg; base += GRP) {
            int idx = base + ln;
            bool on = idx < deg;
            int s = adj[r0 + (on ? idx : 0)];
            float v[H];
            if constexpr (H == 4) {
                float4 sv = reinterpret_cast<const float4*>(ssrc)[s];
                v[0] = sv.x; v[1] = sv.y; v[2] = sv.z; v[3] = sv.w;
            } else {
                v[0] = ssrc[s];
            }
#pragma unroll
            for (int h = 0; h < H; ++h) {
                float t = v[h] + sd[h];
                t = t > 0.f ? t : 0.2f * t;
                float av = on ? __expf(t) : 0.f;
                l[h] += av;
                if (on) a_tab[gid][idx * H + h] = av;
            }
            if (on) s_tab[gid][idx] = s;
        }
        // butterfly sum within group (off-critical-path: result used only in epilogue)
#pragma unroll
        for (int off = GRP / 2; off; off >>= 1)
#pragma unroll
            for (int h = 0; h < H; ++h) l[h] += __shfl_xor(l[h], off, 64);

        // ---- pass 2: table-driven gather, 4-deep unroll ----
        int j = 0;
        for (; j + 3 < deg; j += 4) {
            int s0 = s_tab[gid][j],     s1 = s_tab[gid][j + 1];
            int s2 = s_tab[gid][j + 2], s3 = s_tab[gid][j + 3];
            float a0 = a_tab[gid][j * H + hA],       a1 = a_tab[gid][(j + 1) * H + hA];
            float a2 = a_tab[gid][(j + 2) * H + hA], a3 = a_tab[gid][(j + 3) * H + hA];
            uint4 u0 = *reinterpret_cast<const uint4*>(hbl + (size_t)s0 * ROW_U);
            uint4 u1 = *reinterpret_cast<const uint4*>(hbl + (size_t)s1 * ROW_U);
            uint4 u2 = *reinterpret_cast<const uint4*>(hbl + (size_t)s2 * ROW_U);
            uint4 u3 = *reinterpret_cast<const uint4*>(hbl + (size_t)s3 * ROW_U);
            acc[0] += a0 * bflo(u0.x); acc[1] += a0 * bfhi(u0.x);
            acc[2] += a0 * bflo(u0.y); acc[3] += a0 * bfhi(u0.y);
            acc[4] += a0 * bflo(u0.z); acc[5] += a0 * bfhi(u0.z);
            acc[6] += a0 * bflo(u0.w); acc[7] += a0 * bfhi(u0.w);
            acc[0] += a1 * bflo(u1.x); acc[1] += a1 * bfhi(u1.x);
            acc[2] += a1 * bflo(u1.y); acc[3] += a1 * bfhi(u1.y);
            acc[4] += a1 * bflo(u1.z); acc[5] += a1 * bfhi(u1.z);
            acc[6] += a1 * bflo(u1.w); acc[7] += a1 * bfhi(u1.w);
            acc[0] += a2 * bflo(u2.x); acc[1] += a2 * bfhi(u2.x);
            acc[2] += a2 * bflo(u2.y); acc[3] += a2 * bfhi(u2.y);
            acc[4] += a2 * bflo(u2.z); acc[5] += a2 * bfhi(u2.z);
            acc[6] += a2 * bflo(u2.w); acc[7] += a2 * bfhi(u2.w);
            acc[0] += a3 * bflo(u3.x); acc[1] += a3 * bfhi(u3.x);
            acc[2] += a3 * bflo(u3.y); acc[3] += a3 * bfhi(u3.y);
            acc[4] += a3 * bflo(u3.z); acc[5] += a3 * bfhi(u3.z);
            acc[6] += a3 * bflo(u3.w); acc[7] += a3 * bfhi(u3.w);
        }
        for (; j < deg; ++j) {
            int sj = s_tab[gid][j];
            float al = a_tab[gid][j * H + hA];
            uint4 u = *reinterpret_cast<const uint4*>(hbl + (size_t)sj * ROW_U);
            acc[0] += al * bflo(u.x); acc[1] += al * bfhi(u.x);
            acc[2] += al * bflo(u.y); acc[3] += al * bfhi(u.y);
            acc[4] += al * bflo(u.z); acc[5] += al * bfhi(u.z);
            acc[6] += al * bflo(u.w); acc[7] += al * bfhi(u.w);
        }
    } else {
        // ---- general path (deg > 64): sum pre-pass, recompute alpha in pass 2 ----
        for (int e = r0 + ln; e < r1; e += GRP) {
            int s = adj[e];
#pragma unroll
            for (int h = 0; h < H; ++h) {
                float t = ssrc[s * H + h] + sd[h];
                t = t > 0.f ? t : 0.2f * t;
                l[h] += __expf(t);
            }
        }
#pragma unroll
        for (int off = GRP / 2; off; off >>= 1)
#pragma unroll
            for (int h = 0; h < H; ++h) l[h] += __shfl_xor(l[h], off, 64);
        float sdh = sd[hA];
        for (int e = r0; e < r1; ++e) {
            int s = adj[e];
            float t = ssrc[s * H + hA] + sdh;
            t = t > 0.f ? t : 0.2f * t;
            float al = __expf(t);
            uint4 u = *reinterpret_cast<const uint4*>(hbl + (size_t)s * ROW_U);
            acc[0] += al * bflo(u.x); acc[1] += al * bfhi(u.x);
            acc[2] += al * bflo(u.y); acc[3] += al * bfhi(u.y);
            acc[4] += al * bflo(u.z); acc[5] += al * bfhi(u.z);
            acc[6] += al * bflo(u.w); acc[7] += al * bfhi(u.w);
        }
    }

    // ---- epilogue: normalize, bias, activation, store ----
    float invl = __builtin_amdgcn_rcpf(l[hA]);
#pragma unroll
    for (int f = 0; f < FPLn; ++f) {
        float v = acc[f] * invl + bias[ln * FPLn + f];
        if (ELU) v = v > 0.f ? v : (__expf(v) - 1.f);
        acc[f] = v;
    }
    if constexpr (OUT_BF16) {
        unsigned* op = (unsigned*)outp + (size_t)n * ROW_U + ln * ULN;
        uint4 u = {packbf(acc[0], acc[1]), packbf(acc[2], acc[3]),
                   packbf(acc[4], acc[5]), packbf(acc[6], acc[7])};
        *reinterpret_cast<uint4*>(op) = u;
    } else {
        float* op = (float*)outp + (size_t)n * HC + ln * FPLn;
        *reinterpret_cast<float4*>(op) = make_float4(acc[0], acc[1], acc[2], acc[3]);
        *reinterpret_cast<float4*>(op + 4) = make_float4(acc[4], acc[5], acc[6], acc[7]);
    }
}

// ---------- launch ----------
extern "C" void kernel_launch(void* const* d_in, const int* in_sizes, int n_in,
                              void* d_out, int out_size, void* d_ws, size_t ws_size,
                              hipStream_t stream) {
    const float* x   = (const float*)d_in[0];
    const int*   ei  = (const int*)d_in[1];
    const float* W1  = (const float*)d_in[2];
    const float* as1 = (const float*)d_in[3];
    const float* ad1 = (const float*)d_in[4];
    const float* b1  = (const float*)d_in[5];
    const float* W2  = (const float*)d_in[6];
    const float* as2 = (const float*)d_in[7];
    const float* ad2 = (const float*)d_in[8];
    const float* b2  = (const float*)d_in[9];
    float* out = (float*)d_out;

    const int N  = in_sizes[0] / 128;   // 50000
    const int E  = in_sizes[1] / 2;     // 800000
    const int ET = E + N;
    const int* src = ei;
    const int* dst = ei + E;

    // workspace (4B units)
    unsigned* ws = (unsigned*)d_ws;
    unsigned* xb    = ws;                              // N*64  (x bf16)
    unsigned* h1b   = xb    + (size_t)N * 64;          // N*128
    unsigned* agg1b = h1b   + (size_t)N * 128;         // N*128
    unsigned* h2b   = agg1b + (size_t)N * 128;         // N*64
    unsigned* Wt1   = h2b   + (size_t)N * 64;          // 16384
    unsigned* Wt2   = Wt1   + 16384;                   // 16384
    float*    ssrc1 = (float*)(Wt2 + 16384);           // N*4
    float*    sdst1 = ssrc1 + (size_t)N * 4;           // N*4
    float*    ssrc2 = sdst1 + (size_t)N * 4;           // N
    float*    sdst2 = ssrc2 + N;                       // N
    int*      deg   = (int*)(sdst2 + N);               // N (reused as cursor)
    int*      rowst = deg + N;                         // N+1
    int*      bsums = rowst + N + 1;                   // 64
    int*      adj   = bsums + 64;                      // ET

    const int B = 256;
    auto blocks = [](size_t n, int b) { return (int)((n + b - 1) / b); };
    const int nscan = (N + SCAN_ELEMS - 1) / SCAN_ELEMS;

    // ---- fused prep (deg zeroed first; prep also counts edges) ----
    hipMemsetAsync(deg, 0, (size_t)N * 4, stream);
    {
        int NX2 = N * 64, NW1 = 128 * 256, NW2 = 256 * 128;
        size_t tot = (size_t)NX2 + NW1 + NW2 + E;
        prep_k<<<blocks(tot, B), B, 0, stream>>>(x, W1, W2, dst, xb, (unsigned short*)Wt1,
                                                 (unsigned short*)Wt2, deg, NX2, NW1, NW2, E);
    }

    // ---- CSR build ----
    scan1_k<<<nscan, SCAN_BLK, 0, stream>>>(deg, rowst, bsums, N);
    scan2_k<<<1, 64, 0, stream>>>(bsums, nscan);
    scan3_init_k<<<blocks(N + 1, B), B, 0, stream>>>(rowst, bsums, adj, deg, N, ET);
    scatter_k<<<blocks(E, B), B, 0, stream>>>(src, dst, E, deg, adj);

    // ---- layer 1 ----
    {
        dim3 g((N + 127) / 128, 256 / 64);
        gemm_mfma_k<128, 256><<<g, 256, 0, stream>>>(xb, (const unsigned*)Wt1, (unsigned short*)h1b, N);
    }
    score_b_k<4, 64><<<blocks((size_t)N * 4, B), B, 0, stream>>>(h1b, as1, ad1, ssrc1, sdst1, N);
    // GRP=32: 2 nodes/wave, 8 nodes/block
    node_agg_k<4, 64, 32, true, true><<<(N + 7) / 8, 256, 0, stream>>>(rowst, adj, ssrc1, sdst1, h1b, b1, agg1b, N);

    // ---- layer 2 ----
    {
        dim3 g((N + 127) / 128, 128 / 64);
        gemm_mfma_k<256, 128><<<g, 256, 0, stream>>>(agg1b, (const unsigned*)Wt2, (unsigned short*)h2b, N);
    }
    score_b_k<1, 128><<<blocks(N, B), B, 0, stream>>>(h2b, as2, ad2, ssrc2, sdst2, N);
    // GRP=16: 4 nodes/wave, 16 nodes/block
    node_agg_k<1, 128, 16, false, false><<<(N + 15) / 16, 256, 0, stream>>>(rowst, adj, ssrc2, sdst2, h2b, b2, out, N);
}

// Round 10
// 244.835 us; speedup vs baseline: 1.1236x; 1.0421x over previous
//
#include <hip/hip_runtime.h>
#include <cmath>

typedef __attribute__((ext_vector_type(8))) short bf16x8;
typedef __attribute__((ext_vector_type(4))) float f32x4;

// ---------- bf16 pack/unpack ----------
static __device__ __forceinline__ unsigned short f2bf(float f) {
    unsigned u = __float_as_uint(f);
    unsigned r = (u + 0x7fffu + ((u >> 16) & 1u)) >> 16;   // RNE
    return (unsigned short)r;
}
static __device__ __forceinline__ unsigned packbf(float a, float b) {
    return (unsigned)f2bf(a) | ((unsigned)f2bf(b) << 16);
}
static __device__ __forceinline__ float bflo(unsigned u) { return __uint_as_float(u << 16); }
static __device__ __forceinline__ float bfhi(unsigned u) { return __uint_as_float(u & 0xffff0000u); }

// ---------- fused prep: x->bf16, W1/W2 transpose->bf16, edge count ----------
__global__ void prep_k(const float* __restrict__ x, const float* __restrict__ W1,
                       const float* __restrict__ W2, const int* __restrict__ dst,
                       unsigned* __restrict__ xb,
                       unsigned short* __restrict__ Wt1, unsigned short* __restrict__ Wt2,
                       int* __restrict__ deg, int NX2, int NW1, int NW2, int E) {
    int i = blockIdx.x * blockDim.x + threadIdx.x;
    if (i < NX2) {
        float2 v = reinterpret_cast<const float2*>(x)[i];
        xb[i] = packbf(v.x, v.y);
        return;
    }
    i -= NX2;
    if (i < NW1) { int nn = i / 128, k = i % 128; Wt1[i] = f2bf(W1[(size_t)k * 256 + nn]); return; }
    i -= NW1;
    if (i < NW2) { int nn = i / 256, k = i % 256; Wt2[i] = f2bf(W2[(size_t)k * 128 + nn]); return; }
    i -= NW2;
    if (i < E) atomicAdd(&deg[dst[i]], 1);
}

#define SCAN_BLK 256
#define SCAN_ELEMS 2048

// scan1: deg[i]+1 (implicit self-loop)
__global__ void scan1_k(const int* __restrict__ deg, int* __restrict__ rowstart,
                        int* __restrict__ bsums, int N) {
    __shared__ int sh[SCAN_BLK];
    int t = threadIdx.x;
    int base = blockIdx.x * SCAN_ELEMS + t * 8;
    int vals[8];
    int sum = 0;
#pragma unroll
    for (int i = 0; i < 8; ++i) {
        int idx = base + i;
        vals[i] = (idx < N) ? (deg[idx] + 1) : 0;
        sum += vals[i];
    }
    sh[t] = sum;
    __syncthreads();
    for (int off = 1; off < SCAN_BLK; off <<= 1) {
        int v = (t >= off) ? sh[t - off] : 0;
        __syncthreads();
        sh[t] += v;
        __syncthreads();
    }
    int run = sh[t] - sum;
    if (t == SCAN_BLK - 1) bsums[blockIdx.x] = sh[t];
#pragma unroll
    for (int i = 0; i < 8; ++i) {
        int idx = base + i;
        if (idx < N) rowstart[idx] = run;
        run += vals[i];
    }
}
// wave-parallel exclusive scan of block sums (nb <= 64)
__global__ void scan2_k(int* __restrict__ bsums, int nb) {
    int lane = threadIdx.x;
    int own = (lane < nb) ? bsums[lane] : 0;
    int v = own;
    for (int off = 1; off < 64; off <<= 1) {
        int t = __shfl_up(v, off, 64);
        if (lane >= off) v += t;
    }
    if (lane < nb) bsums[lane] = v - own;
}
// scan3 + initadj fused
__global__ void scan3_init_k(int* __restrict__ rowstart, const int* __restrict__ bsums,
                             int* __restrict__ adj, int* __restrict__ cursor, int N, int total) {
    int i = blockIdx.x * blockDim.x + threadIdx.x;
    if (i < N) {
        int r = rowstart[i] + bsums[i / SCAN_ELEMS];
        rowstart[i] = r;
        adj[r] = i;          // self-loop first
        cursor[i] = r + 1;
    } else if (i == N) {
        rowstart[N] = total;
    }
}
__global__ void scatter_k(const int* __restrict__ src, const int* __restrict__ dst, int E,
                          int* __restrict__ cursor, int* __restrict__ adj) {
    int e = blockIdx.x * blockDim.x + threadIdx.x;
    if (e >= E) return;
    int pos = atomicAdd(&cursor[dst[e]], 1);
    adj[pos] = src[e];
}

// ---------- MFMA GEMM + fused attention scores ----------
// Yb[N,NOUT](bf16) = Ab[N,K](bf16) @ Wt[NOUT,K](bf16)^T
// Epilogue also computes ssrc/sdst: per-row dot of this block's 64 columns with
// a_src/a_dst. Layer1 (C=64): block = one head -> plain store. Layer2 (C=128):
// 2 col-blocks -> f32 atomicAdd (2 contributors: commutative, deterministic).
template<int K, int NOUT, int H, int C>
__global__ __launch_bounds__(256) void gemm_score_k(const unsigned* __restrict__ Ab,
                                                    const unsigned* __restrict__ Bt,
                                                    unsigned short* __restrict__ Yb,
                                                    const float* __restrict__ asrc,
                                                    const float* __restrict__ adst,
                                                    float* __restrict__ ssrc,
                                                    float* __restrict__ sdst, int N) {
    __shared__ unsigned short As[128 * 64];
    __shared__ unsigned short Bs[64 * 64];
    __shared__ float sred[2][2][128];   // [wc][src/dst][row]
    int tid = threadIdx.x;
    int lane = tid & 63, wid = tid >> 6;
    int wm = wid >> 1, wc = wid & 1;
    int m0 = blockIdx.x * 128;
    int n0 = blockIdx.y * 64;

    f32x4 acc[4][2] = {};

    for (int k0 = 0; k0 < K; k0 += 64) {
#pragma unroll
        for (int p = 0; p < 4; ++p) {
            int gl = p * 256 + tid;
            int row = gl >> 3, g = gl & 7;
            int grow = m0 + row; if (grow >= N) grow = N - 1;
            uint4 v = *reinterpret_cast<const uint4*>(Ab + (size_t)grow * (K / 2) + k0 / 2 + g * 4);
            *reinterpret_cast<uint4*>((char*)As + row * 128 + ((g ^ (row & 7)) << 4)) = v;
        }
#pragma unroll
        for (int p = 0; p < 2; ++p) {
            int gl = p * 256 + tid;
            int row = gl >> 3, g = gl & 7;
            uint4 v = *reinterpret_cast<const uint4*>(Bt + (size_t)(n0 + row) * (K / 2) + k0 / 2 + g * 4);
            *reinterpret_cast<uint4*>((char*)Bs + row * 128 + ((g ^ (row & 7)) << 4)) = v;
        }
        __syncthreads();

        bf16x8 bfrag[2][2];
#pragma unroll
        for (int kk = 0; kk < 2; ++kk)
#pragma unroll
            for (int no = 0; no < 2; ++no) {
                int row = wc * 32 + no * 16 + (lane & 15);
                int g = kk * 4 + (lane >> 4);
                bfrag[kk][no] = *reinterpret_cast<const bf16x8*>((char*)Bs + row * 128 + ((g ^ (row & 7)) << 4));
            }
#pragma unroll
        for (int mo = 0; mo < 4; ++mo) {
#pragma unroll
            for (int kk = 0; kk < 2; ++kk) {
                int row = wm * 64 + mo * 16 + (lane & 15);
                int g = kk * 4 + (lane >> 4);
                bf16x8 afrag = *reinterpret_cast<const bf16x8*>((char*)As + row * 128 + ((g ^ (row & 7)) << 4));
                acc[mo][0] = __builtin_amdgcn_mfma_f32_16x16x32_bf16(afrag, bfrag[kk][0], acc[mo][0], 0, 0, 0);
                acc[mo][1] = __builtin_amdgcn_mfma_f32_16x16x32_bf16(afrag, bfrag[kk][1], acc[mo][1], 0, 0, 0);
            }
        }
        __syncthreads();
    }

    // ---- Yb store ----
#pragma unroll
    for (int mo = 0; mo < 4; ++mo)
#pragma unroll
        for (int no = 0; no < 2; ++no) {
            int col = n0 + wc * 32 + no * 16 + (lane & 15);
            int rbase = m0 + wm * 64 + mo * 16 + (lane >> 4) * 4;
#pragma unroll
            for (int j = 0; j < 4; ++j) {
                int row = rbase + j;
                if (row < N) Yb[(size_t)row * NOUT + col] = f2bf(acc[mo][no][j]);
            }
        }

    // ---- fused score epilogue ----
    // coefficients for this thread's two columns (flat [H*C] layout == col index)
    float cs0, cs1, cd0, cd1;
    {
        int c0 = n0 + wc * 32 + (lane & 15);
        cs0 = asrc[c0]; cd0 = adst[c0];
        cs1 = asrc[c0 + 16]; cd1 = adst[c0 + 16];
    }
#pragma unroll
    for (int mo = 0; mo < 4; ++mo) {
        float ps[4], pd[4];
#pragma unroll
        for (int j = 0; j < 4; ++j) {
            ps[j] = acc[mo][0][j] * cs0 + acc[mo][1][j] * cs1;
            pd[j] = acc[mo][0][j] * cd0 + acc[mo][1][j] * cd1;
        }
#pragma unroll
        for (int off = 8; off; off >>= 1)
#pragma unroll
            for (int j = 0; j < 4; ++j) {
                ps[j] += __shfl_xor(ps[j], off, 64);
                pd[j] += __shfl_xor(pd[j], off, 64);
            }
        if ((lane & 15) == 0) {
            int rl = wm * 64 + mo * 16 + (lane >> 4) * 4;
#pragma unroll
            for (int j = 0; j < 4; ++j) {
                sred[wc][0][rl + j] = ps[j];
                sred[wc][1][rl + j] = pd[j];
            }
        }
    }
    __syncthreads();
    if (tid < 128) {
        int grow = m0 + tid;
        if (grow < N) {
            float fs = sred[0][0][tid] + sred[1][0][tid];
            float fd = sred[0][1][tid] + sred[1][1][tid];
            if constexpr (C <= 64) {
                // one block per head: plain store
                int hh = n0 / C;
                ssrc[(size_t)grow * H + hh] = fs;
                sdst[(size_t)grow * H + hh] = fd;
            } else {
                // multiple col-blocks per head: accumulate (buffer pre-zeroed)
                atomicAdd(&ssrc[grow], fs);
                atomicAdd(&sdst[grow], fd);
            }
        }
    }
}

// ---------- fused per-node softmax + bf16 gather-aggregate + epilogue ----------
// One GRP-lane group per node; softmax without max-subtract; unnormalized alpha
// in per-group LDS tables; 1/l folded into epilogue.
template<int H, int C, int GRP, bool ELU, bool OUT_BF16>
__global__ void node_agg_k(const int* __restrict__ rowstart, const int* __restrict__ adj,
                           const float* __restrict__ ssrc, const float* __restrict__ sdst,
                           const unsigned* __restrict__ hb, const float* __restrict__ bias,
                           void* __restrict__ outp, int N) {
    constexpr int HC = H * C;
    constexpr int ROW_U = HC / 2;           // packed uints per row
    constexpr int ULN = ROW_U / GRP;        // uints per lane (=4: 16B)
    constexpr int FPLn = ULN * 2;           // features per lane (=8)
    constexpr int NG = 64 / GRP;            // groups (nodes) per wave
    constexpr int NGB = 4 * NG;             // groups per block (4 waves)
    int lane = threadIdx.x & 63;
    int w = threadIdx.x >> 6;
    int g = lane / GRP, ln = lane % GRP;
    int gid = w * NG + g;
    int n = blockIdx.x * NGB + gid;
    if (n >= N) return;

    __shared__ int   s_tab[NGB][64];
    __shared__ float a_tab[NGB][64 * H];

    int r0 = rowstart[n], r1 = rowstart[n + 1];
    int deg = r1 - r0;

    float sd[H];
#pragma unroll
    for (int h = 0; h < H; ++h) sd[h] = sdst[n * H + h];

    int hA = (ln * FPLn) / C;
    const unsigned* hbl = hb + ln * ULN;
    float acc[FPLn];
#pragma unroll
    for (int f = 0; f < FPLn; ++f) acc[f] = 0.f;
    float l[H];
#pragma unroll
    for (int h = 0; h < H; ++h) l[h] = 0.f;

    if (deg <= 64) {
        // ---- pass 1: strided chunks of GRP edges; fill (s, alpha) tables ----
        for (int base = 0; base < deg; base += GRP) {
            int idx = base + ln;
            bool on = idx < deg;
            int s = adj[r0 + (on ? idx : 0)];
            float v[H];
            if constexpr (H == 4) {
                float4 sv = reinterpret_cast<const float4*>(ssrc)[s];
                v[0] = sv.x; v[1] = sv.y; v[2] = sv.z; v[3] = sv.w;
            } else {
                v[0] = ssrc[s];
            }
#pragma unroll
            for (int h = 0; h < H; ++h) {
                float t = v[h] + sd[h];
                t = t > 0.f ? t : 0.2f * t;
                float av = on ? __expf(t) : 0.f;
                l[h] += av;
                if (on) a_tab[gid][idx * H + h] = av;
            }
            if (on) s_tab[gid][idx] = s;
        }
#pragma unroll
        for (int off = GRP / 2; off; off >>= 1)
#pragma unroll
            for (int h = 0; h < H; ++h) l[h] += __shfl_xor(l[h], off, 64);

        // ---- pass 2: table-driven gather, 4-deep unroll ----
        int j = 0;
        for (; j + 3 < deg; j += 4) {
            int s0 = s_tab[gid][j],     s1 = s_tab[gid][j + 1];
            int s2 = s_tab[gid][j + 2], s3 = s_tab[gid][j + 3];
            float a0 = a_tab[gid][j * H + hA],       a1 = a_tab[gid][(j + 1) * H + hA];
            float a2 = a_tab[gid][(j + 2) * H + hA], a3 = a_tab[gid][(j + 3) * H + hA];
            uint4 u0 = *reinterpret_cast<const uint4*>(hbl + (size_t)s0 * ROW_U);
            uint4 u1 = *reinterpret_cast<const uint4*>(hbl + (size_t)s1 * ROW_U);
            uint4 u2 = *reinterpret_cast<const uint4*>(hbl + (size_t)s2 * ROW_U);
            uint4 u3 = *reinterpret_cast<const uint4*>(hbl + (size_t)s3 * ROW_U);
            acc[0] += a0 * bflo(u0.x); acc[1] += a0 * bfhi(u0.x);
            acc[2] += a0 * bflo(u0.y); acc[3] += a0 * bfhi(u0.y);
            acc[4] += a0 * bflo(u0.z); acc[5] += a0 * bfhi(u0.z);
            acc[6] += a0 * bflo(u0.w); acc[7] += a0 * bfhi(u0.w);
            acc[0] += a1 * bflo(u1.x); acc[1] += a1 * bfhi(u1.x);
            acc[2] += a1 * bflo(u1.y); acc[3] += a1 * bfhi(u1.y);
            acc[4] += a1 * bflo(u1.z); acc[5] += a1 * bfhi(u1.z);
            acc[6] += a1 * bflo(u1.w); acc[7] += a1 * bfhi(u1.w);
            acc[0] += a2 * bflo(u2.x); acc[1] += a2 * bfhi(u2.x);
            acc[2] += a2 * bflo(u2.y); acc[3] += a2 * bfhi(u2.y);
            acc[4] += a2 * bflo(u2.z); acc[5] += a2 * bfhi(u2.z);
            acc[6] += a2 * bflo(u2.w); acc[7] += a2 * bfhi(u2.w);
            acc[0] += a3 * bflo(u3.x); acc[1] += a3 * bfhi(u3.x);
            acc[2] += a3 * bflo(u3.y); acc[3] += a3 * bfhi(u3.y);
            acc[4] += a3 * bflo(u3.z); acc[5] += a3 * bfhi(u3.z);
            acc[6] += a3 * bflo(u3.w); acc[7] += a3 * bfhi(u3.w);
        }
        for (; j < deg; ++j) {
            int sj = s_tab[gid][j];
            float al = a_tab[gid][j * H + hA];
            uint4 u = *reinterpret_cast<const uint4*>(hbl + (size_t)sj * ROW_U);
            acc[0] += al * bflo(u.x); acc[1] += al * bfhi(u.x);
            acc[2] += al * bflo(u.y); acc[3] += al * bfhi(u.y);
            acc[4] += al * bflo(u.z); acc[5] += al * bfhi(u.z);
            acc[6] += al * bflo(u.w); acc[7] += al * bfhi(u.w);
        }
    } else {
        // ---- general path (deg > 64): sum pre-pass, recompute alpha in pass 2 ----
        for (int e = r0 + ln; e < r1; e += GRP) {
            int s = adj[e];
#pragma unroll
            for (int h = 0; h < H; ++h) {
                float t = ssrc[s * H + h] + sd[h];
                t = t > 0.f ? t : 0.2f * t;
                l[h] += __expf(t);
            }
        }
#pragma unroll
        for (int off = GRP / 2; off; off >>= 1)
#pragma unroll
            for (int h = 0; h < H; ++h) l[h] += __shfl_xor(l[h], off, 64);
        float sdh = sd[hA];
        for (int e = r0; e < r1; ++e) {
            int s = adj[e];
            float t = ssrc[s * H + hA] + sdh;
            t = t > 0.f ? t : 0.2f * t;
            float al = __expf(t);
            uint4 u = *reinterpret_cast<const uint4*>(hbl + (size_t)s * ROW_U);
            acc[0] += al * bflo(u.x); acc[1] += al * bfhi(u.x);
            acc[2] += al * bflo(u.y); acc[3] += al * bfhi(u.y);
            acc[4] += al * bflo(u.z); acc[5] += al * bfhi(u.z);
            acc[6] += al * bflo(u.w); acc[7] += al * bfhi(u.w);
        }
    }

    // ---- epilogue: normalize, bias, activation, store ----
    float invl = __builtin_amdgcn_rcpf(l[hA]);
#pragma unroll
    for (int f = 0; f < FPLn; ++f) {
        float v = acc[f] * invl + bias[ln * FPLn + f];
        if (ELU) v = v > 0.f ? v : (__expf(v) - 1.f);
        acc[f] = v;
    }
    if constexpr (OUT_BF16) {
        unsigned* op = (unsigned*)outp + (size_t)n * ROW_U + ln * ULN;
        uint4 u = {packbf(acc[0], acc[1]), packbf(acc[2], acc[3]),
                   packbf(acc[4], acc[5]), packbf(acc[6], acc[7])};
        *reinterpret_cast<uint4*>(op) = u;
    } else {
        float* op = (float*)outp + (size_t)n * HC + ln * FPLn;
        *reinterpret_cast<float4*>(op) = make_float4(acc[0], acc[1], acc[2], acc[3]);
        *reinterpret_cast<float4*>(op + 4) = make_float4(acc[4], acc[5], acc[6], acc[7]);
    }
}

// ---------- launch ----------
extern "C" void kernel_launch(void* const* d_in, const int* in_sizes, int n_in,
                              void* d_out, int out_size, void* d_ws, size_t ws_size,
                              hipStream_t stream) {
    const float* x   = (const float*)d_in[0];
    const int*   ei  = (const int*)d_in[1];
    const float* W1  = (const float*)d_in[2];
    const float* as1 = (const float*)d_in[3];
    const float* ad1 = (const float*)d_in[4];
    const float* b1  = (const float*)d_in[5];
    const float* W2  = (const float*)d_in[6];
    const float* as2 = (const float*)d_in[7];
    const float* ad2 = (const float*)d_in[8];
    const float* b2  = (const float*)d_in[9];
    float* out = (float*)d_out;

    const int N  = in_sizes[0] / 128;   // 50000
    const int E  = in_sizes[1] / 2;     // 800000
    const int ET = E + N;
    const int* src = ei;
    const int* dst = ei + E;

    // workspace (4B units)
    unsigned* ws = (unsigned*)d_ws;
    unsigned* xb    = ws;                              // N*64  (x bf16)
    unsigned* h1b   = xb    + (size_t)N * 64;          // N*128
    unsigned* agg1b = h1b   + (size_t)N * 128;         // N*128
    unsigned* h2b   = agg1b + (size_t)N * 128;         // N*64
    unsigned* Wt1   = h2b   + (size_t)N * 64;          // 16384
    unsigned* Wt2   = Wt1   + 16384;                   // 16384
    float*    ssrc1 = (float*)(Wt2 + 16384);           // N*4
    float*    sdst1 = ssrc1 + (size_t)N * 4;           // N*4
    float*    ssrc2 = sdst1 + (size_t)N * 4;           // N
    float*    sdst2 = ssrc2 + N;                       // N
    int*      deg   = (int*)(sdst2 + N);               // N (reused as cursor)
    int*      rowst = deg + N;                         // N+1
    int*      bsums = rowst + N + 1;                   // 64
    int*      adj   = bsums + 64;                      // ET

    const int B = 256;
    auto blocks = [](size_t n, int b) { return (int)((n + b - 1) / b); };
    const int nscan = (N + SCAN_ELEMS - 1) / SCAN_ELEMS;

    // ---- zero ssrc2/sdst2/deg in one shot (contiguous) + fused prep ----
    hipMemsetAsync(ssrc2, 0, (size_t)N * 3 * 4, stream);
    {
        int NX2 = N * 64, NW1 = 128 * 256, NW2 = 256 * 128;
        size_t tot = (size_t)NX2 + NW1 + NW2 + E;
        prep_k<<<blocks(tot, B), B, 0, stream>>>(x, W1, W2, dst, xb, (unsigned short*)Wt1,
                                                 (unsigned short*)Wt2, deg, NX2, NW1, NW2, E);
    }

    // ---- CSR build ----
    scan1_k<<<nscan, SCAN_BLK, 0, stream>>>(deg, rowst, bsums, N);
    scan2_k<<<1, 64, 0, stream>>>(bsums, nscan);
    scan3_init_k<<<blocks(N + 1, B), B, 0, stream>>>(rowst, bsums, adj, deg, N, ET);
    scatter_k<<<blocks(E, B), B, 0, stream>>>(src, dst, E, deg, adj);

    // ---- layer 1 (GEMM + fused scores) ----
    {
        dim3 g((N + 127) / 128, 256 / 64);
        gemm_score_k<128, 256, 4, 64><<<g, 256, 0, stream>>>(
            xb, (const unsigned*)Wt1, (unsigned short*)h1b, as1, ad1, ssrc1, sdst1, N);
    }
    // GRP=32: 2 nodes/wave, 8 nodes/block
    node_agg_k<4, 64, 32, true, true><<<(N + 7) / 8, 256, 0, stream>>>(rowst, adj, ssrc1, sdst1, h1b, b1, agg1b, N);

    // ---- layer 2 (GEMM + fused scores via atomics) ----
    {
        dim3 g((N + 127) / 128, 128 / 64);
        gemm_score_k<256, 128, 1, 128><<<g, 256, 0, stream>>>(
            agg1b, (const unsigned*)Wt2, (unsigned short*)h2b, as2, ad2, ssrc2, sdst2, N);
    }
    // GRP=16: 4 nodes/wave, 16 nodes/block
    node_agg_k<1, 128, 16, false, false><<<(N + 15) / 16, 256, 0, stream>>>(rowst, adj, ssrc2, sdst2, h2b, b2, out, N);
}